// Round 4
// baseline (416.828 us; speedup 1.0000x reference)
//
#include <hip/hip_runtime.h>
#include <cstdint>
#include <cstddef>

#define BB 32
#define NN 1024
#define CIN 128
#define FF 64
#define NOUT 10
#define CAP 128
#define EPSV 1e-5f

// non-temporal float4 load: stream-once data (A, x) must not evict gather-hot rows.
typedef float vf4 __attribute__((ext_vector_type(4)));
__device__ __forceinline__ float4 ldnt(const float4* p) {
    vf4 v = __builtin_nontemporal_load((const vf4*)p);
    return make_float4(v.x, v.y, v.z, v.w);
}

// ---------------- fused front: [0,8192) CSR, [8192,10240) x@W0 gemm, [10240] gmax seed ----
// unchanged from R3 (proven): CSR N-trim + NT loads + analytic relu(b2) gmax seed.
__global__ __launch_bounds__(256) void k_front(const float* __restrict__ A,
                                               const float* __restrict__ x,
                                               const float* __restrict__ W0,
                                               const int* __restrict__ Nn,
                                               const float* __restrict__ b2f,
                                               float* __restrict__ gmax,
                                               unsigned short* __restrict__ adj,
                                               int* __restrict__ cnt,
                                               float* __restrict__ c1,
                                               float* __restrict__ c2,
                                               float* __restrict__ T) {
    __shared__ __align__(16) float Wl[64 * 64];    // 16 KB
    int tid = threadIdx.x;
    int wave = tid >> 6, lane = tid & 63;
    if (blockIdx.x >= 10240) {
        for (int i = tid; i < BB * 64; i += 256)
            gmax[i] = fmaxf(b2f[i & 63], 0.f);
        return;
    }
    if (blockIdx.x >= 8192) {
        int gid = blockIdx.x - 8192;        // gid%8 == b%8: XCD matches spmm
        int b = gid & 31;
        int cch = gid >> 5;
        if (cch * 16 >= Nn[b]) return;
        int row0 = (b << 10) + cch * 16;
        int rsub = lane >> 4, f0 = (lane & 15) * 4;
        int r = row0 + wave * 4 + rsub;
        const float4* xr = (const float4*)(x + (size_t)r * CIN);
        float4 acc = {0.f, 0.f, 0.f, 0.f};
#pragma unroll
        for (int kc = 0; kc < 2; ++kc) {
            if (kc) __syncthreads();
            for (int t = tid; t < 64 * 16; t += 256)
                ((float4*)Wl)[t] = ((const float4*)W0)[kc * 1024 + t];
            __syncthreads();
#pragma unroll 4
            for (int k4 = 0; k4 < 16; ++k4) {
                float4 xv = ldnt(xr + kc * 16 + k4);
                float4 w0 = *(const float4*)&Wl[(k4 * 4 + 0) * 64 + f0];
                float4 w1 = *(const float4*)&Wl[(k4 * 4 + 1) * 64 + f0];
                float4 w2 = *(const float4*)&Wl[(k4 * 4 + 2) * 64 + f0];
                float4 w3 = *(const float4*)&Wl[(k4 * 4 + 3) * 64 + f0];
                acc.x += xv.x * w0.x; acc.y += xv.x * w0.y; acc.z += xv.x * w0.z; acc.w += xv.x * w0.w;
                acc.x += xv.y * w1.x; acc.y += xv.y * w1.y; acc.z += xv.y * w1.z; acc.w += xv.y * w1.w;
                acc.x += xv.z * w2.x; acc.y += xv.z * w2.y; acc.z += xv.z * w2.z; acc.w += xv.z * w2.w;
                acc.x += xv.w * w3.x; acc.y += xv.w * w3.y; acc.z += xv.w * w3.z; acc.w += xv.w * w3.w;
            }
        }
        *(float4*)&T[(size_t)r * 64 + f0] = acc;
    } else {
        int r = blockIdx.x * 4 + wave;
        int b = r >> 10;
        int Nb = Nn[b];
        int rl = r & 1023;
        if (rl >= Nb) {
            if (lane == 0) {
                cnt[r] = 0;
                float D = 1.0f / sqrtf(1.0f + EPSV);
                c1[r] = D;
                c2[r] = D * D;
            }
            return;
        }
        unsigned short* adjs = ((unsigned short*)Wl) + wave * CAP;
        const float4* Arow = (const float4*)(A + (size_t)r * NN);
        int nch = (Nb + 255) >> 8;
        float4 z4 = {0.f, 0.f, 0.f, 0.f};
        float4 v0 = ldnt(Arow + lane);
        float4 v1 = ldnt(Arow + 64 + lane);
        float4 v2 = (nch > 2) ? ldnt(Arow + 128 + lane) : z4;
        float4 v3 = (nch > 3) ? ldnt(Arow + 192 + lane) : z4;
        int c = 0;
        unsigned long long lt = (lane == 0) ? 0ULL : ((1ULL << lane) - 1ULL);
        float4 vv[4] = {v0, v1, v2, v3};
#pragma unroll
        for (int it = 0; it < 4; ++it) {
            float4 v = vv[it];
            int j0 = it * 256 + lane * 4;
            unsigned long long m0 = __ballot(v.x != 0.f);
            unsigned long long m1 = __ballot(v.y != 0.f);
            unsigned long long m2 = __ballot(v.z != 0.f);
            unsigned long long m3 = __ballot(v.w != 0.f);
            int before = __popcll(m0 & lt) + __popcll(m1 & lt) +
                         __popcll(m2 & lt) + __popcll(m3 & lt);
            int p = c + before;
            if (v.x != 0.f) { if (p < CAP) adjs[p] = (unsigned short)(j0 + 0); ++p; }
            if (v.y != 0.f) { if (p < CAP) adjs[p] = (unsigned short)(j0 + 1); ++p; }
            if (v.z != 0.f) { if (p < CAP) adjs[p] = (unsigned short)(j0 + 2); ++p; }
            if (v.w != 0.f) { if (p < CAP) adjs[p] = (unsigned short)(j0 + 3); ++p; }
            c += __popcll(m0) + __popcll(m1) + __popcll(m2) + __popcll(m3);
        }
        int cc = (c > CAP) ? CAP : c;
        uint32_t* dst = (uint32_t*)(adj + (size_t)r * CAP);
        if (lane * 2 < cc) dst[lane] = ((const uint32_t*)adjs)[lane];
        if (lane == 0) {
            cnt[r] = cc;
            float D = 1.0f / sqrtf((float)c + 1.0f + EPSV);
            c1[r] = D;
            c2[r] = D * D;
        }
    }
}

// ---------------- layer-1 SpMM + self + bias + relu + pool score (R3-proven shape) ----
__global__ __launch_bounds__(256) void k_spmm(const unsigned short* __restrict__ adj,
                                              const int* __restrict__ cnt,
                                              const float* __restrict__ c1,
                                              const float* __restrict__ c2,
                                              const float* __restrict__ T,
                                              const float* __restrict__ bias,
                                              float* __restrict__ X,
                                              const float* __restrict__ p,
                                              float* __restrict__ y,
                                              const int* __restrict__ Nn) {
    __shared__ __align__(16) float c1s[NN];
    int b   = blockIdx.x & 31;
    int cch = blockIdx.x >> 5;
    int Nb = Nn[b];
    if (cch * 16 >= Nb) return;
    int tid = threadIdx.x;
    int n4 = (Nb + 3) >> 2;
    if (tid < n4) ((float4*)c1s)[tid] = ((const float4*)(c1 + (b << 10)))[tid];
    __syncthreads();
    int wave = tid >> 6, lane = tid & 63;
    int r0 = (b << 10) + cch * 16 + wave * 4;
    const float* Tb = T + ((size_t)(b << 10) << 6);
    float bv = bias[lane];
    float pv = p[lane];
    float pp = pv * pv;
    for (int s = 32; s; s >>= 1) pp += __shfl_xor(pp, s, 64);
    float ppinv = 1.0f / sqrtf(pp);
#pragma unroll
    for (int rr = 0; rr < 4; ++rr) {
        int r = r0 + rr;
        int rl = r & 1023;
        if (rl >= Nb) break;
        const unsigned short* arow = adj + (size_t)r * CAP;
        int n = cnt[r];
        float acc0 = 0.f, acc1 = 0.f, acc2 = 0.f, acc3 = 0.f;
        int t = 0;
        for (; t + 4 <= n; t += 4) {
            ushort4 j4 = *(const ushort4*)(arow + t);
            acc0 += c1s[j4.x] * Tb[((int)j4.x << 6) + lane];
            acc1 += c1s[j4.y] * Tb[((int)j4.y << 6) + lane];
            acc2 += c1s[j4.z] * Tb[((int)j4.z << 6) + lane];
            acc3 += c1s[j4.w] * Tb[((int)j4.w << 6) + lane];
        }
        for (; t < n; ++t) {
            int j = arow[t];
            acc0 += c1s[j] * Tb[(j << 6) + lane];
        }
        float acc = (acc0 + acc1) + (acc2 + acc3);
        float o = c1s[rl] * acc + c2[r] * T[((size_t)r << 6) + lane] + bv;
        o = fmaxf(o, 0.f);
        X[((size_t)r << 6) + lane] = o;
        float a = o * pv;
        for (int s = 32; s; s >>= 1) a += __shfl_xor(a, s, 64);
        if (lane == 0) y[r] = a * ppinv;
    }
}

// ---------------- fused pool: rank (u64 keys, every block ranks all nodes) + deg + coeffs
// 16 blocks/graph. u64 key (mono(y)<<10)|idx makes one compare equal the stable
// argsort tie-break. Every block computes full nm in LDS (cheap: 2 ops/pair), then
// its 64-row slice gets masked degree (0/1-exact, lane-parallel) and coefficients:
//   cg[r]  = nm*D*tanh(y)   (gather coeff, premultiplied)
//   c1[r]  = nm*D           (row outer coeff; ==0 marks dead row)
//   cs[r]  = nm*D*D*tanh(y) (self coeff)
__global__ __launch_bounds__(256) void k_rankdeg(const float* __restrict__ y,
                                                 const float* __restrict__ maskSrc,
                                                 const int* __restrict__ nsrc,
                                                 const int* __restrict__ Nn,
                                                 const unsigned short* __restrict__ adj,
                                                 const int* __restrict__ cnt,
                                                 float* __restrict__ nmOut,
                                                 int* __restrict__ ncur,
                                                 float* __restrict__ cg,
                                                 float* __restrict__ c1o,
                                                 float* __restrict__ cso) {
    __shared__ __align__(16) float yv[NN];
    __shared__ __align__(16) unsigned long long kv[NN];
    __shared__ float nml[NN];
    int b = blockIdx.x >> 4;
    int sub = blockIdx.x & 15;
    int tid = threadIdx.x;
    const float INF = __builtin_inff();
    int Nb = Nn[b];
    if ((sub << 6) >= Nb) return;          // slice fully dead; nothing downstream reads it
    {
        float4 v;
        if (tid * 4 < Nb) {
            v = ((const float4*)(y + (b << 10)))[tid];
            float4 m = ((const float4*)(maskSrc + (b << 10)))[tid];
            v.x = (m.x > 0.f) ? v.x : INF;
            v.y = (m.y > 0.f) ? v.y : INF;
            v.z = (m.z > 0.f) ? v.z : INF;
            v.w = (m.w > 0.f) ? v.w : INF;
        } else {
            v.x = INF; v.y = INF; v.z = INF; v.w = INF;
        }
        ((float4*)yv)[tid] = v;
    }
    int n = nsrc[b];
    const float RM = (float)(1.0 - 0.8);   // 0.2f, matches jax f32 semantics
    int nrem = (int)((float)n * RM);
    if (sub == 0 && tid == 0) ncur[b] = n - nrem;
    __syncthreads();
#pragma unroll
    for (int t = 0; t < 4; ++t) {          // build order keys
        int i = tid + (t << 8);
        unsigned int u = __float_as_uint(yv[i]);
        u ^= (unsigned int)((int)u >> 31) | 0x80000000u;   // monotone float->uint
        kv[i] = ((unsigned long long)u << 10) | (unsigned int)i;
    }
    __syncthreads();
    // ranks for ALL 1024 nodes: 4 per thread (full nm needed for deg)
    unsigned long long k0 = kv[tid], k1 = kv[tid + 256],
                       k2 = kv[tid + 512], k3 = kv[tid + 768];
    int r0 = 0, r1 = 0, r2 = 0, r3 = 0;
    int nkc = (Nb + 1) >> 1;               // tail entry (odd Nb) is an INF key: counts 0
#pragma unroll 4
    for (int c = 0; c < nkc; ++c) {
        ulonglong2 a = ((const ulonglong2*)kv)[c];
        r0 += (a.x < k0) + (a.y < k0);
        r1 += (a.x < k1) + (a.y < k1);
        r2 += (a.x < k2) + (a.y < k2);
        r3 += (a.x < k3) + (a.y < k3);
    }
    int rk[4] = {r0, r1, r2, r3};
#pragma unroll
    for (int t = 0; t < 4; ++t) {
        int i = tid + (t << 8);
        nml[i] = (yv[i] < INF && rk[t] >= nrem) ? 1.f : 0.f;
    }
    __syncthreads();
    // own 64-row slice: nm store + masked degree + coefficients (wave per row)
    int wave = tid >> 6, lane = tid & 63;
    for (int rd = 0; rd < 16; ++rd) {
        int i = (sub << 6) + (rd << 2) + wave;
        int gr = (b << 10) + i;
        if (i >= Nb) {                      // pad slice tail: next pool's mask stage
            if (lane == 0) nmOut[gr] = 0.f; // float4-reads up to 3 past Nb
            continue;
        }
        float m = nml[i];
        float s = 0.f;
        if (m != 0.f) {
            int nn = cnt[gr];
            const unsigned short* ar = adj + (size_t)gr * CAP;
            if (lane < nn)      s  = nml[ar[lane]];
            if (lane + 64 < nn) s += nml[ar[lane + 64]];
            for (int sh = 32; sh; sh >>= 1) s += __shfl_xor(s, sh, 64);
        }
        if (lane == 0) {
            nmOut[gr] = m;
            float D = 1.0f / sqrtf(m * s + 1.0f + EPSV);
            float th = tanhf(yv[i]);        // tanh(INF)=1, always multiplied by m
            cg[gr]  = (m * D) * th;
            c1o[gr] = m * D;
            cso[gr] = m * (D * D) * th;
        }
    }
}

// ---------------- layers 2/3: SpMM-aggregate (coeffs premult) + fused agg@W + bias +
// relu + (score | gmax). Replaces k_mid+k_spmm: aggregate-first matches the reference
// ((L@x)@W). Per wave: 4 sequential row-gathers into aggl, then one 4-row LDS
// mini-gemm (float4 W, padded agg -> conflict-free). Dead rows (c1==0) skipped;
// their gmax contribution relu(b2) is covered by the analytic seed.
__global__ __launch_bounds__(256) void k_spmmW(const unsigned short* __restrict__ adj,
                                               const int* __restrict__ cnt,
                                               const float* __restrict__ cg,
                                               const float* __restrict__ c1,
                                               const float* __restrict__ cs,
                                               const float* __restrict__ Xin,
                                               const float* __restrict__ W,
                                               const float* __restrict__ bias,
                                               const float* __restrict__ p,
                                               float* __restrict__ y,
                                               float* __restrict__ Xout,
                                               float* __restrict__ gmax,
                                               const int* __restrict__ Nn) {
    __shared__ __align__(16) float Wl[64 * 64];     // 16 KB
    __shared__ __align__(16) float cgs[NN];         // 4 KB
    __shared__ __align__(16) float aggl[4][4][68];  // padded: bank-conflict-free gemm reads
    __shared__ float4 red4[4][16];
    int b   = blockIdx.x & 31;
    int cch = blockIdx.x >> 5;
    int Nb = Nn[b];
    if (cch * 16 >= Nb) return;
    int tid = threadIdx.x;
    for (int t = tid; t < 64 * 16; t += 256)
        ((float4*)Wl)[t] = ((const float4*)W)[t];
    int n4 = (Nb + 3) >> 2;
    if (tid < n4) ((float4*)cgs)[tid] = ((const float4*)(cg + (b << 10)))[tid];
    __syncthreads();
    int wave = tid >> 6, lane = tid & 63;
    int r0 = (b << 10) + cch * 16 + wave * 4;
    const float* Xb = Xin + ((size_t)(b << 10) << 6);
    int umask = 0;
#pragma unroll
    for (int rr = 0; rr < 4; ++rr) {
        int r = r0 + rr;
        int rl = r & 1023;
        float aggv = 0.f;
        if (rl < Nb) {
            float c1r = c1[r];              // 0 iff pool-dropped (wave-uniform)
            if (c1r != 0.f) {
                umask |= 1 << rr;
                const unsigned short* arow = adj + (size_t)r * CAP;
                int n = cnt[r];
                float acc0 = 0.f, acc1 = 0.f, acc2 = 0.f, acc3 = 0.f;
                int t = 0;
                for (; t + 4 <= n; t += 4) {
                    ushort4 j4 = *(const ushort4*)(arow + t);
                    acc0 += cgs[j4.x] * Xb[((int)j4.x << 6) + lane];
                    acc1 += cgs[j4.y] * Xb[((int)j4.y << 6) + lane];
                    acc2 += cgs[j4.z] * Xb[((int)j4.z << 6) + lane];
                    acc3 += cgs[j4.w] * Xb[((int)j4.w << 6) + lane];
                }
                for (; t < n; ++t) {
                    int j = arow[t];
                    acc0 += cgs[j] * Xb[(j << 6) + lane];
                }
                float acc = (acc0 + acc1) + (acc2 + acc3);
                aggv = c1r * acc + cs[r] * Xin[((size_t)r << 6) + lane];
            }
        }
        aggl[wave][rr][lane] = aggv;        // zero for dead rows
    }
    // per-wave 4-row mini-gemm: lane = (row rsub, f-quad f0); wave-local (no barrier)
    int rsub = lane >> 4, f0 = (lane & 15) * 4;
    float4 o4 = *(const float4*)&bias[f0];
#pragma unroll 16
    for (int k = 0; k < 64; ++k) {
        float a = aggl[wave][rsub][k];
        float4 w = *(const float4*)&Wl[(k << 6) + f0];
        o4.x = fmaf(a, w.x, o4.x); o4.y = fmaf(a, w.y, o4.y);
        o4.z = fmaf(a, w.z, o4.z); o4.w = fmaf(a, w.w, o4.w);
    }
    o4.x = fmaxf(o4.x, 0.f); o4.y = fmaxf(o4.y, 0.f);
    o4.z = fmaxf(o4.z, 0.f); o4.w = fmaxf(o4.w, 0.f);
    bool live = (umask >> rsub) & 1;
    int rOut = r0 + rsub;
    if (Xout != nullptr && live)
        *(float4*)&Xout[((size_t)rOut << 6) + f0] = o4;
    if (p != nullptr) {
        float4 p4 = *(const float4*)&p[f0];
        float pp = p4.x * p4.x + p4.y * p4.y + p4.z * p4.z + p4.w * p4.w;
        for (int s = 8; s; s >>= 1) pp += __shfl_xor(pp, s, 64);   // within 16-lane group
        float ppinv = 1.0f / sqrtf(pp);
        float a = o4.x * p4.x + o4.y * p4.y + o4.z * p4.z + o4.w * p4.w;
        for (int s = 8; s; s >>= 1) a += __shfl_xor(a, s, 64);
        if ((lane & 15) == 0 && live) y[rOut] = a * ppinv;
    }
    if (gmax != nullptr) {
        float4 m4 = o4;   // dead rows contribute relu(b2): covered by the seed
        m4.x = fmaxf(m4.x, __shfl_xor(m4.x, 16, 64));
        m4.y = fmaxf(m4.y, __shfl_xor(m4.y, 16, 64));
        m4.z = fmaxf(m4.z, __shfl_xor(m4.z, 16, 64));
        m4.w = fmaxf(m4.w, __shfl_xor(m4.w, 16, 64));
        m4.x = fmaxf(m4.x, __shfl_xor(m4.x, 32, 64));
        m4.y = fmaxf(m4.y, __shfl_xor(m4.y, 32, 64));
        m4.z = fmaxf(m4.z, __shfl_xor(m4.z, 32, 64));
        m4.w = fmaxf(m4.w, __shfl_xor(m4.w, 32, 64));
        if (lane < 16) red4[wave][lane] = m4;
        __syncthreads();
        if (wave == 0 && lane < 16) {
            float4 a0 = red4[0][lane], a1 = red4[1][lane];
            float4 a2 = red4[2][lane], a3 = red4[3][lane];
            float4 mm;
            mm.x = fmaxf(fmaxf(a0.x, a1.x), fmaxf(a2.x, a3.x));
            mm.y = fmaxf(fmaxf(a0.y, a1.y), fmaxf(a2.y, a3.y));
            mm.z = fmaxf(fmaxf(a0.z, a1.z), fmaxf(a2.z, a3.z));
            mm.w = fmaxf(fmaxf(a0.w, a1.w), fmaxf(a2.w, a3.w));
            int base = (b << 6) + lane * 4;
            atomicMax((int*)&gmax[base + 0], __float_as_int(mm.x));
            atomicMax((int*)&gmax[base + 1], __float_as_int(mm.y));
            atomicMax((int*)&gmax[base + 2], __float_as_int(mm.z));
            atomicMax((int*)&gmax[base + 3], __float_as_int(mm.w));
        }
    }
}

// ---------------- final fc from the fused global-max buffer ----------------
__global__ __launch_bounds__(64) void k_fc(const float* __restrict__ gmax,
                                           const float* __restrict__ Wfc,
                                           const float* __restrict__ bfc,
                                           float* __restrict__ out) {
    __shared__ float gl[64];
    int b = blockIdx.x, lane = threadIdx.x;
    gl[lane] = gmax[(b << 6) + lane];
    __syncthreads();
    if (lane < NOUT) {
        float acc = bfc[lane];
        for (int k = 0; k < 64; ++k) acc += gl[k] * Wfc[k * NOUT + lane];
        out[b * NOUT + lane] = acc;
    }
}

extern "C" void kernel_launch(void* const* d_in, const int* in_sizes, int n_in,
                              void* d_out, int out_size, void* d_ws, size_t ws_size,
                              hipStream_t stream) {
    const float* x    = (const float*)d_in[0];
    const float* A    = (const float*)d_in[1];
    const float* mask = (const float*)d_in[2];
    const int*   Nn   = (const int*)d_in[3];
    const float* W0   = (const float*)d_in[4];
    const float* b0   = (const float*)d_in[5];
    const float* W1   = (const float*)d_in[6];
    const float* b1   = (const float*)d_in[7];
    const float* W2   = (const float*)d_in[8];
    const float* b2   = (const float*)d_in[9];
    const float* p0   = (const float*)d_in[10];
    const float* p1   = (const float*)d_in[11];
    const float* Wfc  = (const float*)d_in[12];
    const float* bfc  = (const float*)d_in[13];
    float* out = (float*)d_out;

    char* ws = (char*)d_ws;
    size_t off = 0;
    auto alloc = [&](size_t bytes) -> void* {
        void* p = ws + off;
        off = (off + bytes + 255) & ~(size_t)255;
        return p;
    };
    unsigned short* adj = (unsigned short*)alloc((size_t)BB * NN * CAP * 2);
    int*   cnt  = (int*)  alloc((size_t)BB * NN * 4);
    float* X    = (float*)alloc((size_t)BB * NN * 64 * 4);   // layer-1 output o1
    float* T    = (float*)alloc((size_t)BB * NN * 64 * 4);   // x@W0, then layer-2 output o2
    float* c1   = (float*)alloc((size_t)BB * NN * 4);        // layer-1 c1, then row coeff
    float* c2   = (float*)alloc((size_t)BB * NN * 4);        // layer-1 c2, then self coeff
    float* cg   = (float*)alloc((size_t)BB * NN * 4);        // premult gather coeff
    float* y    = (float*)alloc((size_t)BB * NN * 4);
    float* nm0  = (float*)alloc((size_t)BB * NN * 4);
    float* nm1  = (float*)alloc((size_t)BB * NN * 4);
    int*   nc0  = (int*)  alloc((size_t)BB * 4);
    int*   nc1  = (int*)  alloc((size_t)BB * 4);
    float* gmax = (float*)alloc((size_t)BB * 64 * 4);

    // 1) fused: CSR build (8192) + x@W0 gemm (2048) + gmax relu(b2) seed (1 block)
    k_front<<<8192 + 2048 + 1, 256, 0, stream>>>(A, x, W0, Nn, b2, gmax,
                                                 adj, cnt, c1, c2, T);
    // 2) layer-1 SpMM + pool-1 score
    k_spmm<<<2048, 256, 0, stream>>>(adj, cnt, c1, c2, T, b0, X, p0, y, Nn);
    // 3) pool 1: rank + masked deg + coeffs (cg, c1, c2)
    k_rankdeg<<<BB * 16, 256, 0, stream>>>(y, mask, Nn, Nn, adj, cnt,
                                           nm0, nc0, cg, c1, c2);
    // 4) layer-2 aggregate + agg@W1 + pool-2 score  (X -> T)
    k_spmmW<<<2048, 256, 0, stream>>>(adj, cnt, cg, c1, c2, X, W1, b1,
                                      p1, y, T, nullptr, Nn);
    // 5) pool 2
    k_rankdeg<<<BB * 16, 256, 0, stream>>>(y, nm0, nc0, Nn, adj, cnt,
                                           nm1, nc1, cg, c1, c2);
    // 6) layer-3 aggregate + agg@W2 + fused global max  (T -> gmax)
    k_spmmW<<<2048, 256, 0, stream>>>(adj, cnt, cg, c1, c2, T, W2, b2,
                                      nullptr, nullptr, nullptr, gmax, Nn);
    // 7) fc from gmax
    k_fc<<<BB, 64, 0, stream>>>(gmax, Wfc, bfc, out);
}